// Round 5
// baseline (244.590 us; speedup 1.0000x reference)
//
#include <hip/hip_runtime.h>

// LinearAttention: N=8, L=S=4096, H=8, D=M=64, fp32.
// phase1 (16 s-splits, MFMA, cooperative): block 256 = 4 waves, 34 KB LDS ->
//   4 blocks/CU (16 waves/CU). Per 32-s k-step: K-waves stage phi(K)*mask,
//   V-waves stage V (bf16 hi/lo, transposed [d][s] with chunk-XOR swizzle,
//   b64 packed writes), ONE barrier, register prefetch of next tile issued
//   after the barrier (vmcnt already drained -> no barrier stall), then each
//   wave reads frags for its 32x32 quadrant (8 b128) + 12 MFMA (hi*hi+hi*lo+
//   lo*hi). acc = 16 VGPR/lane -> small register state, deep MLP.
//   Quadrants are disjoint -> acc written straight to KVp (no LDS park).
// reduce: sums 16 split partials; emits KV^T bf16 hi/lo ([m][d]) + fp32 Ksum.
// phase2 (MFMA, unchanged, verified): Q straight from global, bf16 hi/lo
//   split, no LDS, no barriers; denominator exact fp32.

#define SLEN 4096
#define LLEN 4096
#define NHTOT 64      // N*H
#define HD   512      // H*D row stride in elements
#define NSPLIT 16
#define EPSF 1e-6f

typedef short s16x8 __attribute__((ext_vector_type(8)));
typedef float f32x4 __attribute__((ext_vector_type(4)));

__device__ __forceinline__ float phi(float x) {
    return x > 0.0f ? x + 1.0f : __expf(x);
}

// pack bf16(hi) of two floats into one u32 (a -> low half = lower s index)
__device__ __forceinline__ unsigned pack_hi2(float a, float b) {
    return (__float_as_uint(a) >> 16) | (__float_as_uint(b) & 0xFFFF0000u);
}
// residual after bf16 truncation (exact)
__device__ __forceinline__ float bres(float x) {
    return x - __uint_as_float(__float_as_uint(x) & 0xFFFF0000u);
}
// scalar split for reduce kernel
__device__ __forceinline__ void bsplit(float x, short& hi, short& lo) {
    const unsigned bx = __float_as_uint(x);
    hi = (short)(bx >> 16);
    const float hf = __uint_as_float(bx & 0xFFFF0000u);
    lo = (short)(__float_as_uint(x - hf) >> 16);
}

// ---------------- Phase 1: per-split KV partials via MFMA ----------------
// grid (NSPLIT=16, 64), block 256 = 4 waves, 34 KB LDS -> 4 blocks/CU.
// Block: 256 s-rows in 8 k-steps of 32. Transposed bf16 tiles in shared LDS:
//   element (d, s) at byte d*64 + ((s>>3) ^ ((d>>2)&3))*16 + (s&7)*2.
__global__ __launch_bounds__(256, 4)
void la_phase1(const float* __restrict__ Kg, const float* __restrict__ Vg,
               const float* __restrict__ maskg,
               float* __restrict__ KVp, float* __restrict__ Ksump) {
    __shared__ char  sb[2][16384];  // per buf: KThi|KTlo (at 0,4096) VThi|VTlo (8192,12288)
    __shared__ float ksb[8 * 64];   // ksum partials (2 KB) -> 34 KB total

    const int tid  = threadIdx.x;
    const int w    = tid >> 6;
    const int lane = tid & 63;
    const int nh   = blockIdx.y;
    const int n    = nh >> 3;
    const int h    = nh & 7;
    const int sp   = blockIdx.x;

    // staging role: waves 0-1 stage K, waves 2-3 stage V.
    // idx in [0,128): c = d-chunk (4 floats), q = s-quad (4 rows)
    const bool isK = (w < 2);
    const int idx  = tid & 127;
    const int c    = idx & 15;
    const int q    = idx >> 4;
    const int c4   = c * 4;
    const float* __restrict__ src = isK ? Kg : Vg;
    const int arro = isK ? 0 : 8192;
    // b64 write: chunk16B = (s>>3)=(q>>1), swizzle key (d>>2)&3 = c&3 for all 4 d
    const int woff = (((q >> 1) ^ (c & 3)) << 4) | ((q & 1) << 3);

    // mfma role: wave quadrant (wd, wm); lane r = tile row/col, a = k-group
    const int wd = w & 1, wm = w >> 1;
    const int r  = lane & 15, a = lane >> 4;
    const int cho = ((a ^ ((r >> 2) & 3)) << 4);   // read-side swizzled chunk

    const size_t base = (size_t)n * SLEN * HD + (size_t)h * 64;
    const float* mrow = maskg + (size_t)n * SLEN;
    const int brow0 = sp * 256;

    f32x4 acc[2][2];
    #pragma unroll
    for (int dt = 0; dt < 2; ++dt)
        #pragma unroll
        for (int mt = 0; mt < 2; ++mt)
            acc[dt][mt] = (f32x4){0.f, 0.f, 0.f, 0.f};
    float4 ksp = make_float4(0.f, 0.f, 0.f, 0.f);

    // prologue: prefetch k-step 0 (4 rows x 4 floats per thread)
    float4 p[4];
    float  pm[4];
    #pragma unroll
    for (int j = 0; j < 4; ++j) {
        const int s = brow0 + q * 4 + j;
        p[j] = *(const float4*)(src + base + (size_t)s * HD + c4);
        if (isK) pm[j] = mrow[s];
    }

    #pragma unroll 2
    for (int t = 0; t < 8; ++t) {
        // ---- transform + transposed bf16 hi/lo write to buf[t&1] ----
        char* bb = &sb[t & 1][arro];
        float4 vv[4];
        if (isK) {
            #pragma unroll
            for (int j = 0; j < 4; ++j) {
                float4 kq = p[j];
                const float mm = pm[j];
                kq.x = phi(kq.x) * mm; kq.y = phi(kq.y) * mm;
                kq.z = phi(kq.z) * mm; kq.w = phi(kq.w) * mm;
                ksp.x += kq.x; ksp.y += kq.y; ksp.z += kq.z; ksp.w += kq.w;
                vv[j] = kq;
            }
        } else {
            #pragma unroll
            for (int j = 0; j < 4; ++j) vv[j] = p[j];
        }
        #pragma unroll
        for (int i = 0; i < 4; ++i) {
            const int doff = (c4 + i) * 64 + woff;
            const float x0 = (&vv[0].x)[i], x1 = (&vv[1].x)[i];
            const float x2 = (&vv[2].x)[i], x3 = (&vv[3].x)[i];
            *(uint2*)(bb + doff)        = make_uint2(pack_hi2(x0, x1), pack_hi2(x2, x3));
            *(uint2*)(bb + 4096 + doff) = make_uint2(pack_hi2(bres(x0), bres(x1)),
                                                     pack_hi2(bres(x2), bres(x3)));
        }
        __syncthreads();   // single barrier per k-step (WAR safe: 2 barriers apart)

        // ---- prefetch next k-step AFTER barrier (stays in flight over MFMA) ----
        if (t < 7) {
            #pragma unroll
            for (int j = 0; j < 4; ++j) {
                const int s = brow0 + (t + 1) * 32 + q * 4 + j;
                p[j] = *(const float4*)(src + base + (size_t)s * HD + c4);
                if (isK) pm[j] = mrow[s];
            }
        }

        // ---- frag reads for this wave's quadrant + 12 MFMA ----
        const char* rbK = &sb[t & 1][0];
        const char* rbV = &sb[t & 1][8192];
        s16x8 Ah[2], Al[2], Bh[2], Bl[2];
        #pragma unroll
        for (int dt = 0; dt < 2; ++dt) {
            const int off = ((wd * 2 + dt) * 16 + r) * 64 + cho;
            Ah[dt] = *(const s16x8*)(rbK + off);
            Al[dt] = *(const s16x8*)(rbK + 4096 + off);
        }
        #pragma unroll
        for (int mt = 0; mt < 2; ++mt) {
            const int off = ((wm * 2 + mt) * 16 + r) * 64 + cho;
            Bh[mt] = *(const s16x8*)(rbV + off);
            Bl[mt] = *(const s16x8*)(rbV + 4096 + off);
        }
        #pragma unroll
        for (int dt = 0; dt < 2; ++dt)
            #pragma unroll
            for (int mt = 0; mt < 2; ++mt) {
                acc[dt][mt] = __builtin_amdgcn_mfma_f32_16x16x32_bf16(Ah[dt], Bh[mt], acc[dt][mt], 0, 0, 0);
                acc[dt][mt] = __builtin_amdgcn_mfma_f32_16x16x32_bf16(Ah[dt], Bl[mt], acc[dt][mt], 0, 0, 0);
                acc[dt][mt] = __builtin_amdgcn_mfma_f32_16x16x32_bf16(Al[dt], Bh[mt], acc[dt][mt], 0, 0, 0);
            }
    }

    // ---- ksum block reduce ----
    if (isK) *(float4*)&ksb[q * 64 + c4] = ksp;
    __syncthreads();
    if (tid < 64) {
        float ssum = 0.f;
        #pragma unroll
        for (int rr = 0; rr < 8; ++rr) ssum += ksb[rr * 64 + tid];
        Ksump[((size_t)sp * NHTOT + nh) * 64 + tid] = ssum;
    }

    // ---- direct global write of this wave's disjoint 32x32 quadrant ----
    // D layout: col = r (m within tile), row = a*4 + pp (d within tile)
    float* outp = KVp + ((size_t)sp * NHTOT + nh) * 4096;
    #pragma unroll
    for (int dt = 0; dt < 2; ++dt)
        #pragma unroll
        for (int mt = 0; mt < 2; ++mt)
            #pragma unroll
            for (int pp = 0; pp < 4; ++pp)
                outp[(wd * 32 + dt * 16 + a * 4 + pp) * 64 + wm * 32 + mt * 16 + r] = acc[dt][mt][pp];
}

// ---------------- Reduce + transpose + bf16 split ----------------
// grid (4, 64): block handles m-range [bx*16, bx*16+16) of one nh.
__global__ __launch_bounds__(256)
void la_reduce(const float* __restrict__ KVp, const float* __restrict__ Ksump,
               short* __restrict__ KVThi, short* __restrict__ KVTlo,
               float* __restrict__ Ksum) {
    __shared__ float ld[64 * 20];   // [64 d][16 m], stride 20

    const int nh  = blockIdx.y;
    const int mb  = blockIdx.x * 16;
    const int tid = threadIdx.x;

    const int d    = tid >> 2;
    const int moff = (tid & 3) * 4;
    float4 a = make_float4(0.f, 0.f, 0.f, 0.f);
    #pragma unroll
    for (int s = 0; s < NSPLIT; ++s) {
        const float4 v = *(const float4*)&KVp[((size_t)s * NHTOT + nh) * 4096 + d * 64 + mb + moff];
        a.x += v.x; a.y += v.y; a.z += v.z; a.w += v.w;
    }
    *(float4*)&ld[d * 20 + moff] = a;
    __syncthreads();

    const int mloc = tid >> 4;
    const int d0   = (tid & 15) * 4;
    short hi4[4], lo4[4];
    #pragma unroll
    for (int i = 0; i < 4; ++i)
        bsplit(ld[(d0 + i) * 20 + mloc], hi4[i], lo4[i]);
    const size_t o = (size_t)nh * 4096 + (mb + mloc) * 64 + d0;
    *(short4*)&KVThi[o] = *(short4*)hi4;
    *(short4*)&KVTlo[o] = *(short4*)lo4;

    if (blockIdx.x == 0 && tid < 64) {
        float b = 0.f;
        #pragma unroll
        for (int s = 0; s < NSPLIT; ++s)
            b += Ksump[((size_t)s * NHTOT + nh) * 64 + tid];
        Ksum[nh * 64 + tid] = b;
    }
}

// ---------------- Phase 2: MFMA out = phi(Q) @ KV, normalized ----------------
// (unchanged - verified)
__global__ __launch_bounds__(256)
void la_phase2(const float* __restrict__ Qg,
               const short* __restrict__ KVThi, const short* __restrict__ KVTlo,
               const float* __restrict__ Ksum, float* __restrict__ Og) {
    const int tid  = threadIdx.x;
    const int w    = tid >> 6;
    const int lane = tid & 63;
    const int nh   = blockIdx.y;
    const int n    = nh >> 3;
    const int h    = nh & 7;
    const int l0   = blockIdx.x * 128 + w * 32;

    const int r  = lane & 15;
    const int g4 = lane >> 4;

    const short* bhp = KVThi + (size_t)nh * 4096;
    const short* blp = KVTlo + (size_t)nh * 4096;
    const float* ksp = Ksum + nh * 64;

    f32x4 acc[2][4];
    #pragma unroll
    for (int t = 0; t < 2; ++t)
        #pragma unroll
        for (int u = 0; u < 4; ++u)
            acc[t][u] = (f32x4){0.f, 0.f, 0.f, 0.f};
    float den[2] = {0.f, 0.f};

    #pragma unroll
    for (int g = 0; g < 2; ++g) {
        const int db = g * 32 + g4 * 8;

        s16x8 Bh[4], Bl[4];
        #pragma unroll
        for (int u = 0; u < 4; ++u) {
            Bh[u] = *(const s16x8*)&bhp[(u * 16 + r) * 64 + db];
            Bl[u] = *(const s16x8*)&blp[(u * 16 + r) * 64 + db];
        }
        const float4 k0 = *(const float4*)&ksp[db];
        const float4 k1 = *(const float4*)&ksp[db + 4];

        #pragma unroll
        for (int t = 0; t < 2; ++t) {
            const float* qrow = Qg + ((size_t)(n * LLEN + l0 + t * 16 + r) * 8 + h) * 64 + db;
            float4 q0 = *(const float4*)qrow;
            float4 q1 = *(const float4*)(qrow + 4);
            q0.x = phi(q0.x); q0.y = phi(q0.y); q0.z = phi(q0.z); q0.w = phi(q0.w);
            q1.x = phi(q1.x); q1.y = phi(q1.y); q1.z = phi(q1.z); q1.w = phi(q1.w);

            float dn = den[t];
            dn = fmaf(q0.x, k0.x, dn); dn = fmaf(q0.y, k0.y, dn);
            dn = fmaf(q0.z, k0.z, dn); dn = fmaf(q0.w, k0.w, dn);
            dn = fmaf(q1.x, k1.x, dn); dn = fmaf(q1.y, k1.y, dn);
            dn = fmaf(q1.z, k1.z, dn); dn = fmaf(q1.w, k1.w, dn);
            den[t] = dn;

            s16x8 Ah, Al;
            {
                short hh, ll;
                bsplit(q0.x, hh, ll); Ah[0] = hh; Al[0] = ll;
                bsplit(q0.y, hh, ll); Ah[1] = hh; Al[1] = ll;
                bsplit(q0.z, hh, ll); Ah[2] = hh; Al[2] = ll;
                bsplit(q0.w, hh, ll); Ah[3] = hh; Al[3] = ll;
                bsplit(q1.x, hh, ll); Ah[4] = hh; Al[4] = ll;
                bsplit(q1.y, hh, ll); Ah[5] = hh; Al[5] = ll;
                bsplit(q1.z, hh, ll); Ah[6] = hh; Al[6] = ll;
                bsplit(q1.w, hh, ll); Ah[7] = hh; Al[7] = ll;
            }
            #pragma unroll
            for (int u = 0; u < 4; ++u) {
                acc[t][u] = __builtin_amdgcn_mfma_f32_16x16x32_bf16(Ah, Bh[u], acc[t][u], 0, 0, 0);
                acc[t][u] = __builtin_amdgcn_mfma_f32_16x16x32_bf16(Ah, Bl[u], acc[t][u], 0, 0, 0);
                acc[t][u] = __builtin_amdgcn_mfma_f32_16x16x32_bf16(Al, Bh[u], acc[t][u], 0, 0, 0);
            }
        }
    }

    #pragma unroll
    for (int t = 0; t < 2; ++t) {
        den[t] += __shfl_xor(den[t], 16, 64);
        den[t] += __shfl_xor(den[t], 32, 64);
    }

    #pragma unroll
    for (int t = 0; t < 2; ++t) {
        #pragma unroll
        for (int k = 0; k < 4; ++k) {
            const int ro = g4 * 4 + k;
            const float dk = __shfl(den[t], ro, 64);
            const float z  = 1.0f / (dk + EPSF);
            const int l = l0 + t * 16 + ro;
            float* op = &Og[((size_t)(n * LLEN + l) * 8 + h) * 64 + r];
            #pragma unroll
            for (int u = 0; u < 4; ++u)
                op[u * 16] = acc[t][u][k] * z;
        }
    }
}

extern "C" void kernel_launch(void* const* d_in, const int* in_sizes, int n_in,
                              void* d_out, int out_size, void* d_ws, size_t ws_size,
                              hipStream_t stream) {
    const float* Q    = (const float*)d_in[0];
    const float* K    = (const float*)d_in[1];
    const float* V    = (const float*)d_in[2];
    const float* mask = (const float*)d_in[3];
    float* out = (float*)d_out;

    float* KVp   = (float*)d_ws;                              // [16][64][4096] f32 = 16 MB
    float* Ksump = KVp + (size_t)NSPLIT * NHTOT * 4096;       // [16][64][64] = 256 KB
    float* Ksum  = Ksump + (size_t)NSPLIT * NHTOT * 64;       // [64][64] f32 = 16 KB
    short* KVThi = (short*)(Ksum + NHTOT * 64);               // [64][64m][64d] bf16 = 512 KB
    short* KVTlo = KVThi + (size_t)NHTOT * 4096;              // 512 KB  (total ~17.3 MB, = round-0 proven footprint)
    // every ws element read is written first (no memset needed)

    dim3 g1(NSPLIT, NHTOT);
    la_phase1<<<g1, 256, 0, stream>>>(K, V, mask, KVp, Ksump);

    dim3 gr(4, NHTOT);
    la_reduce<<<gr, 256, 0, stream>>>(KVp, Ksump, KVThi, KVTlo, Ksum);

    dim3 g2(LLEN / 128, NHTOT);
    la_phase2<<<g2, 256, 0, stream>>>(Q, KVThi, KVTlo, Ksum, out);
}